// Round 12
// baseline (954.069 us; speedup 1.0000x reference)
//
#include <hip/hip_runtime.h>
#include <stdint.h>

typedef __bf16 bf16x8 __attribute__((ext_vector_type(8)));
typedef float f32x4 __attribute__((ext_vector_type(4)));
typedef float f32x2 __attribute__((ext_vector_type(2)));

#define MFMA16(a, b, c) __builtin_amdgcn_mfma_f32_16x16x32_bf16((a), (b), (c), 0, 0, 0)

__device__ __forceinline__ float sigf(float x) { return 1.f / (1.f + __expf(-x)); }
__device__ __forceinline__ float tanhfast(float x) { return 1.f - 2.f / (__expf(2.f * x) + 1.f); }
__device__ __forceinline__ float bf2f(uint16_t u) {
  union { float f; uint32_t i; } v; v.i = ((uint32_t)u) << 16; return v.f;
}
__device__ __forceinline__ uint16_t f2bf(float f) {
  union { float f; uint32_t i; } v; v.f = f;
  return (uint16_t)((v.i + 0x7FFFu + ((v.i >> 16) & 1u)) >> 16);
}
// 8 consecutive f32 -> bf16x8 (RNE); p must be 16B-aligned
__device__ __forceinline__ bf16x8 cvt8(const float* __restrict__ p) {
  f32x4 a = *(const f32x4*)p;
  f32x4 b = *(const f32x4*)(p + 4);
  bf16x8 r;
  r[0] = (__bf16)a[0]; r[1] = (__bf16)a[1]; r[2] = (__bf16)a[2]; r[3] = (__bf16)a[3];
  r[4] = (__bf16)b[0]; r[5] = (__bf16)b[1]; r[6] = (__bf16)b[2]; r[7] = (__bf16)b[3];
  return r;
}

// ---------------------------------------------------------------------------
// K0: mf_W f32 [512][1000] -> bf16 padded [512][1024]
// ---------------------------------------------------------------------------
__global__ __launch_bounds__(256) void k_prep(
    const float* __restrict__ mf_W, uint16_t* __restrict__ mfWb) {
  const int idx = blockIdx.x * 256 + threadIdx.x;   // 524288 total
  const int h = idx >> 10, k = idx & 1023;
  const float v = (k < 1000) ? mf_W[(size_t)h * 1000 + k] : 0.f;
  mfWb[idx] = f2bf(v);
}

// ---------------------------------------------------------------------------
// K1: encWb[v][col] = bf16( sum_k enc_emb[v][k]*W_ih[col][k] + b_ih + b_hh )
// ---------------------------------------------------------------------------
__global__ __launch_bounds__(256) void k_encW(
    const float* __restrict__ enc_emb,   // [1002][512]
    const float* __restrict__ W_ih,      // [2048][512]
    const float* __restrict__ b_ih,
    const float* __restrict__ b_hh,
    uint16_t* __restrict__ encWb)        // [1002][2048] bf16
{
  const int w = threadIdx.x >> 6, l = threadIdx.x & 63;
  const int mblk = blockIdx.x & 15;
  const int nblk = blockIdx.x >> 4;
  const int kg = l >> 4;
  const int arow = mblk * 64 + w * 16 + (l & 15);
  const bool rowok = arow < 1002;

  f32x4 acc[4] = {};
  for (int kk = 0; kk < 16; ++kk) {
    const int kc = kk * 32 + kg * 8;
    bf16x8 a = {};
    if (rowok) a = cvt8(enc_emb + (size_t)arow * 512 + kc);
#pragma unroll
    for (int n = 0; n < 4; ++n) {
      const int wrow = nblk * 64 + n * 16 + (l & 15);
      bf16x8 b = cvt8(W_ih + (size_t)wrow * 512 + kc);
      acc[n] = MFMA16(a, b, acc[n]);
    }
  }
  const int orow = mblk * 64 + w * 16 + kg * 4;
#pragma unroll
  for (int n = 0; n < 4; ++n) {
    const int col = nblk * 64 + n * 16 + (l & 15);
    const float bias = b_ih[col] + b_hh[col];
#pragma unroll
    for (int j = 0; j < 4; ++j) {
      const int rrow = orow + j;
      if (rrow < 1002) encWb[(size_t)rrow * 2048 + col] = f2bf(acc[n][j] + bias);
    }
  }
}

// ---------------------------------------------------------------------------
// K2-FUSED: blocks 0..255 = scan; 256..1055 = s-major ext GEMM (round-11,
//     unchanged). SCAN ROLE REDESIGNED (K-split waves):
//     wave w = K-slice (producers 4w..4w+3 == kk tiles 4w..4w+3), computing
//     partial gates for ALL 4 gates' columns. A-fragments load DIRECTLY from
//     hbuf (per-lane 16B: row=l&15, k=prod*32+kg*8) — no LDS staging, no
//     gather barrier. Poll/load/MFMA interleaved => compute starts at the
//     wave's FIRST producer flag, not the block's last. Partials summed in
//     LDS (gbufP, +34-pad) at the single pre-cell barrier. Flag protocol,
//     drain, writer-safety proof unchanged from round 8 (the gbuf barrier
//     still orders all-16-flags>=t before cell). s_setprio(1) on scan waves
//     (T5: role-diverse waves share CUs under fusion).
// ---------------------------------------------------------------------------
__global__ __launch_bounds__(256, 2) void k_fused(
    const int* __restrict__ inp,        // [256][200]
    const float* __restrict__ W_hh,     // [2048][512] f32
    const uint16_t* __restrict__ encWb, // [1002][2048] bf16
    const int* __restrict__ uid, const int* __restrict__ sid,   // [51200]
    const float* __restrict__ user_emb,    // [50000][500]
    const float* __restrict__ skill_emb,   // [500][500]
    const uint16_t* __restrict__ mfWb,     // [512][1024] bf16
    const float* __restrict__ mf_b,        // [512]
    uint16_t* __restrict__ ext,         // [256*200][512] bf16
    uint16_t* __restrict__ hbuf,        // [2][256][512] bf16
    float* __restrict__ hfinal,         // [256][512] f32
    uint32_t* __restrict__ flags,       // [256] x 16-u32 stride (64B lines)
    uint32_t* __restrict__ extCnt)      // [200] x 16-u32 stride (64B lines)
{
  __shared__ __align__(1024) char ldsbuf[65536];

  const int tid = threadIdx.x;
  const int w = tid >> 6, l = tid & 63, kg = l >> 4;

  if (blockIdx.x >= 256) {
    // ================= EXT role (s-major, round-11 verified) =================
    char* As = ldsbuf;   // [64 rows][1024B], XOR-swizzled
    const int bx = blockIdx.x - 256;
    const int s  = bx >> 2;      // timestep 0..199
    const int bq = bx & 3;       // batch quarter

    const int srow = tid >> 2;
    const int q = tid & 3;
    const int m = (bq * 64 + srow) * 200 + s;
    const float* up = user_emb + (size_t)uid[m] * 500;
    const float* sp = skill_emb + (size_t)sid[m] * 500;

    f32x4 acc[4][8] = {};

#pragma unroll
    for (int ks = 0; ks < 2; ++ks) {
      if (ks) __syncthreads();
#pragma unroll
      for (int j = 0; j < 16; ++j) {
        const int e0 = ks * 512 + q * 128 + j * 8;
        bf16x8 av = {};
        if (e0 + 8 <= 500) {
          av = cvt8(up + e0);
        } else if (e0 == 496) {
          f32x4 a4 = *(const f32x4*)(up + 496);
          f32x4 b4 = *(const f32x4*)sp;
          av[0] = (__bf16)a4[0]; av[1] = (__bf16)a4[1]; av[2] = (__bf16)a4[2]; av[3] = (__bf16)a4[3];
          av[4] = (__bf16)b4[0]; av[5] = (__bf16)b4[1]; av[6] = (__bf16)b4[2]; av[7] = (__bf16)b4[3];
        } else if (e0 + 8 <= 1000) {
          av = cvt8(sp + (e0 - 500));
        }
        const int kb = (q * 128 + j * 8) * 2;
        *(bf16x8*)(As + srow * 1024 + (kb ^ ((srow & 7) << 4))) = av;
      }
      __syncthreads();

      for (int kk = 0; kk < 16; ++kk) {
        bf16x8 a[4];
#pragma unroll
        for (int rf = 0; rf < 4; ++rf) {
          const int row = rf * 16 + (l & 15);
          a[rf] = *(const bf16x8*)(As + row * 1024 +
                                   ((kk * 64 + kg * 16) ^ ((row & 7) << 4)));
        }
#pragma unroll
        for (int n = 0; n < 8; ++n) {
          const int col = w * 128 + n * 16 + (l & 15);
          bf16x8 b = *(const bf16x8*)(mfWb + (size_t)col * 1024 + ks * 512 + kk * 32 + kg * 8);
#pragma unroll
          for (int rf = 0; rf < 4; ++rf)
            acc[rf][n] = MFMA16(a[rf], b, acc[rf][n]);
        }
      }
    }

#pragma unroll
    for (int rf = 0; rf < 4; ++rf)
#pragma unroll
      for (int n = 0; n < 8; ++n) {
        const int col = w * 128 + n * 16 + (l & 15);
        const float bias = mf_b[col];
#pragma unroll
        for (int j = 0; j < 4; ++j) {
          const int bl = rf * 16 + kg * 4 + j;
          const size_t grow = (size_t)(bq * 64 + bl) * 200 + s;
          ext[grow * 512 + col] = f2bf(acc[rf][n][j] + bias);
        }
      }
    asm volatile("s_waitcnt vmcnt(0)" ::: "memory");
    __syncthreads();
    if (tid == 0) {
      asm volatile("buffer_wbl2 sc1\n\ts_waitcnt vmcnt(0)" ::: "memory");
      __hip_atomic_fetch_add(extCnt + s * 16, 1u, __ATOMIC_RELAXED, __HIP_MEMORY_SCOPE_AGENT);
    }
    return;
  }

  // ================= SCAN role (K-split waves) =================
  __builtin_amdgcn_s_setprio(1);
  float (*gbufP)[4][16][34] = (float(*)[4][16][34])ldsbuf;        // 34,816 B (+34 pad)
  float (*ctS)[32]          = (float(*)[32])(ldsbuf + 34816);     //  2,048 B
  int (*inpS)[200]          = (int(*)[200])(ldsbuf + 36864);      // 12,800 B

  const int c = blockIdx.x & 15;          // h-slice (32 h)
  const int r = blockIdx.x >> 4;          // rowgroup (16 batch rows)
  const int row0 = r * 16;

  // B-frags: wave w's K-slice (k = (4w+i)*32 + kg*8) for all 8 col-tiles
  // (n = g*2+half -> W_hh row g*512 + c*32 + half*16 + (l&15)). 128 VGPRs.
  bf16x8 wfragK[8][4];
#pragma unroll
  for (int n = 0; n < 8; ++n) {
    const int g = n >> 1, half = n & 1;
    const int wrow = g * 512 + c * 32 + half * 16 + (l & 15);
#pragma unroll
    for (int i = 0; i < 4; ++i)
      wfragK[n][i] = cvt8(W_hh + (size_t)wrow * 512 + (w * 4 + i) * 32 + kg * 8);
  }
  for (int e = tid; e < 512; e += 256) ctS[e >> 5][e & 31] = 0.f;
  for (int e = tid; e < 16 * 200; e += 256)
    inpS[e / 200][e % 200] = inp[(row0 + e / 200) * 200 + (e % 200)];

  const int urr = tid >> 4;             // cell: row, 2 consecutive h
  const int uh2 = (tid & 15) << 1;
  const int ub = row0 + urr;

  __syncthreads();

  // ---- prologue: encW(t=0) into acc (gate w tiles; others 0); gated ep
  f32x4 acc[8];
  {
    float en[2][4];
#pragma unroll
    for (int half = 0; half < 2; ++half)
#pragma unroll
      for (int j = 0; j < 4; ++j) {
        const int col = w * 512 + c * 32 + half * 16 + (l & 15);
        en[half][j] = bf2f(encWb[(size_t)inpS[kg * 4 + j][0] * 2048 + col]);
      }
#pragma unroll
    for (int n = 0; n < 8; ++n)
#pragma unroll
      for (int j = 0; j < 4; ++j)
        acc[n][j] = ((n >> 1) == w) ? en[n & 1][j] : 0.f;
  }
  while (__hip_atomic_load(extCnt + 16, __ATOMIC_RELAXED, __HIP_MEMORY_SCOPE_AGENT) < 4u)
    __builtin_amdgcn_s_sleep(1);
  uint32_t ep = __hip_atomic_load(
      (const uint32_t*)(ext + (size_t)ub * 200 * 512 + 512 + c * 32 + uh2),
      __ATOMIC_RELAXED, __HIP_MEMORY_SCOPE_AGENT);

  union AU { uint64_t u[2]; bf16x8 v; };

  for (int t = 0; t < 200; ++t) {
    // ---- poll own 4 producers; A-frags direct hbuf->reg; MFMA as they land
    if (t > 0) {
      const uint16_t* hb = hbuf + (size_t)(t & 1) * (256 * 512);
      const uint16_t* abase = hb + (size_t)(row0 + (l & 15)) * 512 + kg * 8;
      AU afr0, afr1, afr2, afr3;
#define PL(i, afr) { \
    while (__hip_atomic_load(flags + (r * 16 + (w * 4 + i)) * 16, \
                             __ATOMIC_RELAXED, __HIP_MEMORY_SCOPE_AGENT) < (uint32_t)t) \
      __builtin_amdgcn_s_sleep(1); \
    const uint64_t* sp_ = (const uint64_t*)(abase + (w * 4 + i) * 32); \
    afr.u[0] = __hip_atomic_load(sp_,     __ATOMIC_RELAXED, __HIP_MEMORY_SCOPE_AGENT); \
    afr.u[1] = __hip_atomic_load(sp_ + 1, __ATOMIC_RELAXED, __HIP_MEMORY_SCOPE_AGENT); }
#define MT(i, afr) { _Pragma("unroll") \
    for (int n = 0; n < 8; ++n) acc[n] = MFMA16(afr.v, wfragK[n][i], acc[n]); }
      PL(0, afr0) PL(1, afr1)
      MT(0, afr0)
      PL(2, afr2)
      MT(1, afr1)
      PL(3, afr3)
      MT(2, afr2) MT(3, afr3)
#undef PL
#undef MT
    }
    // ---- write K-partials; single barrier; cell sums 4 partials
#pragma unroll
    for (int n = 0; n < 8; ++n) {
      const int g = n >> 1, half = n & 1;
#pragma unroll
      for (int j = 0; j < 4; ++j)
        gbufP[w][g][kg * 4 + j][half * 16 + (l & 15)] = acc[n][j];
    }
    __syncthreads();

    {
      f32x2 sg[4] = {};
#pragma unroll
      for (int g = 0; g < 4; ++g)
#pragma unroll
        for (int wp = 0; wp < 4; ++wp)
          sg[g] += *(const f32x2*)&gbufP[wp][g][urr][uh2];

      float hv[2];
#pragma unroll
      for (int p = 0; p < 2; ++p) {
        const int h = uh2 + p;
        const float ig = sigf(sg[0][p]);
        const float fg = sigf(sg[1][p]);
        const float gg = tanhfast(sg[2][p]);
        const float og = sigf(sg[3][p]);
        const float cv = fg * ctS[urr][h] + ig * gg;
        ctS[urr][h] = cv;
        hv[p] = og * tanhfast(cv);
      }
      if (t < 199) {
        // pre-gate for step t+1: htg = ht * sigmoid(ext[:, t+1, :])
        const float g0 = sigf(bf2f((uint16_t)(ep & 0xFFFFu)));
        const float g1 = sigf(bf2f((uint16_t)(ep >> 16)));
        const uint32_t pk = (uint32_t)f2bf(hv[0] * g0) | ((uint32_t)f2bf(hv[1] * g1) << 16);
        uint32_t* hw = (uint32_t*)(hbuf + (size_t)((t + 1) & 1) * (256 * 512) +
                                   (size_t)ub * 512 + c * 32 + uh2);
        __hip_atomic_store(hw, pk, __ATOMIC_RELAXED, __HIP_MEMORY_SCOPE_AGENT);
      } else {
        hfinal[(size_t)ub * 512 + c * 32 + uh2]     = hv[0];
        hfinal[(size_t)ub * 512 + c * 32 + uh2 + 1] = hv[1];
      }
    }
    // drain stores to coherence point; all waves done; one flag store
    asm volatile("s_waitcnt vmcnt(0)" ::: "memory");
    __syncthreads();
    if (tid == 0)
      __hip_atomic_store(flags + (r * 16 + c) * 16, (uint32_t)(t + 1),
                         __ATOMIC_RELAXED, __HIP_MEMORY_SCOPE_AGENT);

    // ---- prefetch for step t+1 (off signal path): encW -> acc re-init; ep
    if (t < 199) {
      const int tn = t + 1;
      float en[2][4];
#pragma unroll
      for (int half = 0; half < 2; ++half)
#pragma unroll
        for (int j = 0; j < 4; ++j) {
          const int col = w * 512 + c * 32 + half * 16 + (l & 15);
          en[half][j] = bf2f(encWb[(size_t)inpS[kg * 4 + j][tn] * 2048 + col]);
        }
#pragma unroll
      for (int n = 0; n < 8; ++n)
#pragma unroll
        for (int j = 0; j < 4; ++j)
          acc[n][j] = ((n >> 1) == w) ? en[n & 1][j] : 0.f;

      const int te = (t + 2 < 200) ? t + 2 : 199;
      while (__hip_atomic_load(extCnt + te * 16, __ATOMIC_RELAXED, __HIP_MEMORY_SCOPE_AGENT) < 4u)
        __builtin_amdgcn_s_sleep(1);
      ep = __hip_atomic_load(
          (const uint32_t*)(ext + (size_t)ub * 200 * 512 + (size_t)te * 512 + c * 32 + uh2),
          __ATOMIC_RELAXED, __HIP_MEMORY_SCOPE_AGENT);
    }
  }
}

// ---------------------------------------------------------------------------
// K4: out[b] = sigmoid( dot(hfinal[b], dec_W[tgt[b]]) + dec_b[tgt[b]] )
// ---------------------------------------------------------------------------
__global__ __launch_bounds__(256) void k_dec(
    const float* __restrict__ hfinal,   // [256][512]
    const float* __restrict__ dec_W,    // [500][512]
    const float* __restrict__ dec_b,    // [500]
    const int* __restrict__ tgt,        // [256]
    float* __restrict__ out)            // [256]
{
  const int w = threadIdx.x >> 6, l = threadIdx.x & 63;
  const int b = blockIdx.x * 4 + w;
  const int t = tgt[b];
  float s = 0.f;
#pragma unroll
  for (int i = 0; i < 8; ++i) {
    const int k = l + i * 64;
    s += hfinal[(size_t)b * 512 + k] * dec_W[(size_t)t * 512 + k];
  }
#pragma unroll
  for (int m = 32; m; m >>= 1) s += __shfl_xor(s, m, 64);
  if (l == 0) out[b] = sigf(s + dec_b[t]);
}

// ---------------------------------------------------------------------------
extern "C" void kernel_launch(void* const* d_in, const int* in_sizes, int n_in,
                              void* d_out, int out_size, void* d_ws, size_t ws_size,
                              hipStream_t stream) {
  (void)in_sizes; (void)n_in; (void)out_size; (void)ws_size;
  const int*   inp       = (const int*)d_in[0];
  const int*   target_id = (const int*)d_in[1];
  const int*   uid       = (const int*)d_in[2];
  const int*   sid       = (const int*)d_in[3];
  // d_in[4] attempt_sequence: unused by reference
  const float* enc_emb   = (const float*)d_in[5];
  const float* user_emb  = (const float*)d_in[6];
  const float* skill_emb = (const float*)d_in[7];
  const float* mf_W      = (const float*)d_in[8];
  const float* mf_b      = (const float*)d_in[9];
  const float* W_ih      = (const float*)d_in[10];
  const float* W_hh      = (const float*)d_in[11];
  const float* b_ih      = (const float*)d_in[12];
  const float* b_hh      = (const float*)d_in[13];
  const float* dec_W     = (const float*)d_in[14];
  const float* dec_b     = (const float*)d_in[15];

  char* ws = (char*)d_ws;
  uint32_t* flags  = (uint32_t*)(ws);                  //    16,384 B (padded h-flags)
  uint32_t* extCnt = (uint32_t*)(ws + 16384);          //    12,800 B (padded s-counters)
  uint16_t* hbuf   = (uint16_t*)(ws + 32768);          //   524,288 B (bf16 x2 buf)
  float*    hfinal = (float*)   (ws + 557056);         //   524,288 B
  uint16_t* encWb  = (uint16_t*)(ws + 1081344);        // 4,104,192 B (bf16)
  uint16_t* mfWb   = (uint16_t*)(ws + 5185536);        // 1,048,576 B
  uint16_t* ext    = (uint16_t*)(ws + 6234112);        // 52,428,800 B (total ~58.7 MB)

  // zero flags + extCnt every call (in-graph => every replay)
  hipMemsetAsync(ws, 0, 29184, stream);

  k_prep<<<2048, 256, 0, stream>>>(mf_W, mfWb);
  k_encW<<<512,  256, 0, stream>>>(enc_emb, W_ih, b_ih, b_hh, encWb);
  k_fused<<<1056, 256, 0, stream>>>(inp, W_hh, encWb, uid, sid, user_emb, skill_emb,
                                    mfWb, mf_b, ext, hbuf, hfinal, flags, extCnt);
  k_dec<<<64, 256, 0, stream>>>(hfinal, dec_W, dec_b, target_id, (float*)d_out);
}

// Round 13
// 741.161 us; speedup vs baseline: 1.2873x; 1.2873x over previous
//
#include <hip/hip_runtime.h>
#include <stdint.h>

typedef __bf16 bf16x8 __attribute__((ext_vector_type(8)));
typedef float f32x4 __attribute__((ext_vector_type(4)));

#define MFMA16(a, b, c) __builtin_amdgcn_mfma_f32_16x16x32_bf16((a), (b), (c), 0, 0, 0)

__device__ __forceinline__ float sigf(float x) { return 1.f / (1.f + __expf(-x)); }
__device__ __forceinline__ float tanhfast(float x) { return 1.f - 2.f / (__expf(2.f * x) + 1.f); }
__device__ __forceinline__ float bf2f(uint16_t u) {
  union { float f; uint32_t i; } v; v.i = ((uint32_t)u) << 16; return v.f;
}
__device__ __forceinline__ uint16_t f2bf(float f) {
  union { float f; uint32_t i; } v; v.f = f;
  return (uint16_t)((v.i + 0x7FFFu + ((v.i >> 16) & 1u)) >> 16);
}
// 8 consecutive f32 -> bf16x8 (RNE); p must be 16B-aligned
__device__ __forceinline__ bf16x8 cvt8(const float* __restrict__ p) {
  f32x4 a = *(const f32x4*)p;
  f32x4 b = *(const f32x4*)(p + 4);
  bf16x8 r;
  r[0] = (__bf16)a[0]; r[1] = (__bf16)a[1]; r[2] = (__bf16)a[2]; r[3] = (__bf16)a[3];
  r[4] = (__bf16)b[0]; r[5] = (__bf16)b[1]; r[6] = (__bf16)b[2]; r[7] = (__bf16)b[3];
  return r;
}

// ---------------------------------------------------------------------------
// K0: mf_W f32 [512][1000] -> bf16 padded [512][1024]
// ---------------------------------------------------------------------------
__global__ __launch_bounds__(256) void k_prep(
    const float* __restrict__ mf_W, uint16_t* __restrict__ mfWb) {
  const int idx = blockIdx.x * 256 + threadIdx.x;   // 524288 total
  const int h = idx >> 10, k = idx & 1023;
  const float v = (k < 1000) ? mf_W[(size_t)h * 1000 + k] : 0.f;
  mfWb[idx] = f2bf(v);
}

// ---------------------------------------------------------------------------
// K1: encWb[v][col] = bf16( sum_k enc_emb[v][k]*W_ih[col][k] + b_ih + b_hh )
// ---------------------------------------------------------------------------
__global__ __launch_bounds__(256) void k_encW(
    const float* __restrict__ enc_emb,   // [1002][512]
    const float* __restrict__ W_ih,      // [2048][512]
    const float* __restrict__ b_ih,
    const float* __restrict__ b_hh,
    uint16_t* __restrict__ encWb)        // [1002][2048] bf16
{
  const int w = threadIdx.x >> 6, l = threadIdx.x & 63;
  const int mblk = blockIdx.x & 15;
  const int nblk = blockIdx.x >> 4;
  const int kg = l >> 4;
  const int arow = mblk * 64 + w * 16 + (l & 15);
  const bool rowok = arow < 1002;

  f32x4 acc[4] = {};
  for (int kk = 0; kk < 16; ++kk) {
    const int kc = kk * 32 + kg * 8;
    bf16x8 a = {};
    if (rowok) a = cvt8(enc_emb + (size_t)arow * 512 + kc);
#pragma unroll
    for (int n = 0; n < 4; ++n) {
      const int wrow = nblk * 64 + n * 16 + (l & 15);
      bf16x8 b = cvt8(W_ih + (size_t)wrow * 512 + kc);
      acc[n] = MFMA16(a, b, acc[n]);
    }
  }
  const int orow = mblk * 64 + w * 16 + kg * 4;
#pragma unroll
  for (int n = 0; n < 4; ++n) {
    const int col = nblk * 64 + n * 16 + (l & 15);
    const float bias = b_ih[col] + b_hh[col];
#pragma unroll
    for (int j = 0; j < 4; ++j) {
      const int rrow = orow + j;
      if (rrow < 1002) encWb[(size_t)rrow * 2048 + col] = f2bf(acc[n][j] + bias);
    }
  }
}

// ---------------------------------------------------------------------------
// K2-FUSED: blocks 0..255 = scan (ROUND-11 structure, wave=gate, htgS staging);
//     blocks 256..1055 = s-major ext GEMM (round-11, unchanged).
//     SCAN EXCHANGE REPLACED: TAGGED-DATA protocol. Each stored u32 (2 bf16 h)
//     carries a 2-bit gen tag ((t>>1)&3) in the two bf16 LSBs (<=1 ulp).
//     Producer: cell -> tagged agent store. NO drain, NO barrier, NO flag.
//     Consumer: per-wave incremental poll of its 4 producers' 16B — the
//     successful poll IS the gather (one LLC RTT vs round-11's three:
//     drain + flag RTT + gather RTT). Safety: (1) per-location modification
//     order => 2-bit tag distinguishes gen t from t-2 (t-4 cannot resurface);
//     (2) hbuf memset 0xFF in-graph => poison/replay tag=3, first wanted
//     tag=0; (3) write-after-read: block overwrites h(t-1) only after its
//     gbuf barrier, which requires all 16 peers' h(t) tags observed =>
//     peers' gather(t-1) loads completed (program order through MFMA).
// ---------------------------------------------------------------------------
__global__ __launch_bounds__(256, 2) void k_fused(
    const int* __restrict__ inp,        // [256][200]
    const float* __restrict__ W_hh,     // [2048][512] f32
    const uint16_t* __restrict__ encWb, // [1002][2048] bf16
    const int* __restrict__ uid, const int* __restrict__ sid,   // [51200]
    const float* __restrict__ user_emb,    // [50000][500]
    const float* __restrict__ skill_emb,   // [500][500]
    const uint16_t* __restrict__ mfWb,     // [512][1024] bf16
    const float* __restrict__ mf_b,        // [512]
    uint16_t* __restrict__ ext,         // [256*200][512] bf16
    uint16_t* __restrict__ hbuf,        // [2][256][512] bf16 tagged
    float* __restrict__ hfinal,         // [256][512] f32
    uint32_t* __restrict__ extCnt)      // [200] x 16-u32 stride (64B lines)
{
  __shared__ __align__(1024) char ldsbuf[65536];

  const int tid = threadIdx.x;
  const int w = tid >> 6, l = tid & 63, kg = l >> 4;

  if (blockIdx.x >= 256) {
    // ================= EXT role (s-major, round-11 verified) =================
    char* As = ldsbuf;   // [64 rows][1024B], XOR-swizzled
    const int bx = blockIdx.x - 256;
    const int s  = bx >> 2;      // timestep 0..199
    const int bq = bx & 3;       // batch quarter

    const int srow = tid >> 2;
    const int q = tid & 3;
    const int m = (bq * 64 + srow) * 200 + s;
    const float* up = user_emb + (size_t)uid[m] * 500;
    const float* sp = skill_emb + (size_t)sid[m] * 500;

    f32x4 acc[4][8] = {};

#pragma unroll
    for (int ks = 0; ks < 2; ++ks) {
      if (ks) __syncthreads();
#pragma unroll
      for (int j = 0; j < 16; ++j) {
        const int e0 = ks * 512 + q * 128 + j * 8;
        bf16x8 av = {};
        if (e0 + 8 <= 500) {
          av = cvt8(up + e0);
        } else if (e0 == 496) {
          f32x4 a4 = *(const f32x4*)(up + 496);
          f32x4 b4 = *(const f32x4*)sp;
          av[0] = (__bf16)a4[0]; av[1] = (__bf16)a4[1]; av[2] = (__bf16)a4[2]; av[3] = (__bf16)a4[3];
          av[4] = (__bf16)b4[0]; av[5] = (__bf16)b4[1]; av[6] = (__bf16)b4[2]; av[7] = (__bf16)b4[3];
        } else if (e0 + 8 <= 1000) {
          av = cvt8(sp + (e0 - 500));
        }
        const int kb = (q * 128 + j * 8) * 2;
        *(bf16x8*)(As + srow * 1024 + (kb ^ ((srow & 7) << 4))) = av;
      }
      __syncthreads();

      for (int kk = 0; kk < 16; ++kk) {
        bf16x8 a[4];
#pragma unroll
        for (int rf = 0; rf < 4; ++rf) {
          const int row = rf * 16 + (l & 15);
          a[rf] = *(const bf16x8*)(As + row * 1024 +
                                   ((kk * 64 + kg * 16) ^ ((row & 7) << 4)));
        }
#pragma unroll
        for (int n = 0; n < 8; ++n) {
          const int col = w * 128 + n * 16 + (l & 15);
          bf16x8 b = *(const bf16x8*)(mfWb + (size_t)col * 1024 + ks * 512 + kk * 32 + kg * 8);
#pragma unroll
          for (int rf = 0; rf < 4; ++rf)
            acc[rf][n] = MFMA16(a[rf], b, acc[rf][n]);
        }
      }
    }

#pragma unroll
    for (int rf = 0; rf < 4; ++rf)
#pragma unroll
      for (int n = 0; n < 8; ++n) {
        const int col = w * 128 + n * 16 + (l & 15);
        const float bias = mf_b[col];
#pragma unroll
        for (int j = 0; j < 4; ++j) {
          const int bl = rf * 16 + kg * 4 + j;
          const size_t grow = (size_t)(bq * 64 + bl) * 200 + s;
          ext[grow * 512 + col] = f2bf(acc[rf][n][j] + bias);
        }
      }
    asm volatile("s_waitcnt vmcnt(0)" ::: "memory");
    __syncthreads();
    if (tid == 0) {
      asm volatile("buffer_wbl2 sc1\n\ts_waitcnt vmcnt(0)" ::: "memory");
      __hip_atomic_fetch_add(extCnt + s * 16, 1u, __ATOMIC_RELAXED, __HIP_MEMORY_SCOPE_AGENT);
    }
    return;
  }

  // ================= SCAN role (round-11 structure, tagged exchange) =========
  uint16_t* htgS        = (uint16_t*)ldsbuf;                   // 16,384 B swizzled
  float (*gbuf)[16][32] = (float(*)[16][32])(ldsbuf + 16384);  //  8,192 B
  float (*ctS)[32]      = (float(*)[32])(ldsbuf + 24576);      //  2,048 B
  int (*inpS)[200]      = (int(*)[200])(ldsbuf + 26624);       // 12,800 B

  const int c = blockIdx.x & 15;          // h-slice (32 h)
  const int r = blockIdx.x >> 4;          // rowgroup (16 batch rows)
  const int row0 = r * 16;

  // W_hh slice -> bf16 register fragments (persistent, 128 VGPRs)
  bf16x8 wfrag[16][2];
#pragma unroll
  for (int kk = 0; kk < 16; ++kk) {
#pragma unroll
    for (int n = 0; n < 2; ++n) {
      const int wrow = w * 512 + c * 32 + n * 16 + (l & 15);
      wfrag[kk][n] = cvt8(W_hh + (size_t)wrow * 512 + kk * 32 + kg * 8);
    }
  }
  for (int e = tid; e < 512; e += 256) ctS[e >> 5][e & 31] = 0.f;
  for (int e = tid; e < 2048; e += 256) ((uint64_t*)htgS)[e] = 0ull;   // htg(0)=0
  for (int e = tid; e < 16 * 200; e += 256)
    inpS[e / 200][e % 200] = inp[(row0 + e / 200) * 200 + (e % 200)];

  const int grow_ = l >> 2;             // gather: row, 16B chunk
  const int gch = l & 3;
  const int urr = tid >> 4;             // cell: row, 2 consecutive h
  const int uh2 = (tid & 15) << 1;
  const int ub = row0 + urr;

  __syncthreads();

  // ---- prologue: acc(t=0) from encWb; gated ep (ext[:,1]) via agent load
  f32x4 acc[2];
#pragma unroll
  for (int n = 0; n < 2; ++n)
#pragma unroll
    for (int j = 0; j < 4; ++j) {
      const int col = w * 512 + c * 32 + n * 16 + (l & 15);
      acc[n][j] = bf2f(encWb[(size_t)inpS[kg * 4 + j][0] * 2048 + col]);
    }
  while (__hip_atomic_load(extCnt + 16, __ATOMIC_RELAXED, __HIP_MEMORY_SCOPE_AGENT) < 4u)
    __builtin_amdgcn_s_sleep(1);
  uint32_t ep = __hip_atomic_load(
      (const uint32_t*)(ext + (size_t)ub * 200 * 512 + 512 + c * 32 + uh2),
      __ATOMIC_RELAXED, __HIP_MEMORY_SCOPE_AGENT);

  for (int t = 0; t < 200; ++t) {
    // ---- gather h(t): per-wave incremental TAG-POLL (poll IS the gather)
    if (t > 0) {
      const uint32_t tag = (uint32_t)((t >> 1) & 3);
      const uint64_t pat64 = ((uint64_t)((tag & 1u) | ((tag >> 1) << 16))) * 0x0000000100000001ull;
      const uint16_t* hb = hbuf + (size_t)(t & 1) * (256 * 512);
      uint64_t v[4][2];
#pragma unroll
      for (int p = 0; p < 4; ++p) {
        const int prod = w * 4 + p;
        const uint64_t* sp = (const uint64_t*)(hb + (size_t)(row0 + grow_) * 512 + prod * 32 + gch * 8);
        uint64_t a0, a1;
        while (true) {
          a0 = __hip_atomic_load(sp,     __ATOMIC_RELAXED, __HIP_MEMORY_SCOPE_AGENT);
          a1 = __hip_atomic_load(sp + 1, __ATOMIC_RELAXED, __HIP_MEMORY_SCOPE_AGENT);
          if ((a0 & 0x0001000100010001ull) == pat64 &&
              (a1 & 0x0001000100010001ull) == pat64) break;
          __builtin_amdgcn_s_sleep(1);
        }
        v[p][0] = a0; v[p][1] = a1;
      }
      // swizzled LDS writes (bank pattern: 2-way max = free)
#pragma unroll
      for (int p = 0; p < 4; ++p) {
        const int prod = w * 4 + p;
        const int baddr = grow_ * 1024 + (((prod * 64) + gch * 16) ^ ((grow_ & 7) << 4));
        *(uint64_t*)((char*)htgS + baddr)     = v[p][0];
        *(uint64_t*)((char*)htgS + baddr + 8) = v[p][1];
      }
    }
    __syncthreads();

    // ---- gates = acc(prefetched encW) + htg @ W_hh_slice^T
    const int ar = l & 15;
#pragma unroll
    for (int kk = 0; kk < 16; ++kk) {
      bf16x8 a = *(const bf16x8*)((char*)htgS + ar * 1024 +
                                  ((kk * 64 + kg * 16) ^ ((ar & 7) << 4)));
      acc[0] = MFMA16(a, wfrag[kk][0], acc[0]);
      acc[1] = MFMA16(a, wfrag[kk][1], acc[1]);
    }
#pragma unroll
    for (int n = 0; n < 2; ++n)
#pragma unroll
      for (int j = 0; j < 4; ++j)
        gbuf[w][kg * 4 + j][n * 16 + (l & 15)] = acc[n][j];
    __syncthreads();

    // ---- cell update: thread -> (row urr, 2 consecutive h); TAGGED store
    {
      float hv[2];
#pragma unroll
      for (int p = 0; p < 2; ++p) {
        const int h = uh2 + p;
        const float ig = sigf(gbuf[0][urr][h]);
        const float fg = sigf(gbuf[1][urr][h]);
        const float gg = tanhfast(gbuf[2][urr][h]);
        const float og = sigf(gbuf[3][urr][h]);
        const float cv = fg * ctS[urr][h] + ig * gg;
        ctS[urr][h] = cv;
        hv[p] = og * tanhfast(cv);
      }
      if (t < 199) {
        // pre-gate for step t+1: htg = ht * sigmoid(ext[:, t+1, :]);
        // embed gen tag ((t+1)>>1)&3 in the two bf16 LSBs (<=1 ulp each)
        const float g0 = sigf(bf2f((uint16_t)(ep & 0xFFFFu)));
        const float g1 = sigf(bf2f((uint16_t)(ep >> 16)));
        const uint32_t tagn = (uint32_t)(((t + 1) >> 1) & 3);
        const uint32_t tpat = (tagn & 1u) | ((tagn >> 1) << 16);
        uint32_t pk = (uint32_t)f2bf(hv[0] * g0) | ((uint32_t)f2bf(hv[1] * g1) << 16);
        pk = (pk & ~0x00010001u) | tpat;
        uint32_t* hw = (uint32_t*)(hbuf + (size_t)((t + 1) & 1) * (256 * 512) +
                                   (size_t)ub * 512 + c * 32 + uh2);
        __hip_atomic_store(hw, pk, __ATOMIC_RELAXED, __HIP_MEMORY_SCOPE_AGENT);
      } else {
        hfinal[(size_t)ub * 512 + c * 32 + uh2]     = hv[0];
        hfinal[(size_t)ub * 512 + c * 32 + uh2 + 1] = hv[1];
      }
    }
    // NO drain, NO barrier, NO flag — tags carry the ordering.

    // ---- prefetch for step t+1 (hides under next step's tag-poll)
    if (t < 199) {
      const int tn = t + 1;
#pragma unroll
      for (int n = 0; n < 2; ++n)
#pragma unroll
        for (int j = 0; j < 4; ++j) {
          const int col = w * 512 + c * 32 + n * 16 + (l & 15);
          acc[n][j] = bf2f(encWb[(size_t)inpS[kg * 4 + j][tn] * 2048 + col]);
        }
      const int te = (t + 2 < 200) ? t + 2 : 199;
      while (__hip_atomic_load(extCnt + te * 16, __ATOMIC_RELAXED, __HIP_MEMORY_SCOPE_AGENT) < 4u)
        __builtin_amdgcn_s_sleep(1);
      ep = __hip_atomic_load(
          (const uint32_t*)(ext + (size_t)ub * 200 * 512 + (size_t)te * 512 + c * 32 + uh2),
          __ATOMIC_RELAXED, __HIP_MEMORY_SCOPE_AGENT);
    }
  }
}

// ---------------------------------------------------------------------------
// K4: out[b] = sigmoid( dot(hfinal[b], dec_W[tgt[b]]) + dec_b[tgt[b]] )
// ---------------------------------------------------------------------------
__global__ __launch_bounds__(256) void k_dec(
    const float* __restrict__ hfinal,   // [256][512]
    const float* __restrict__ dec_W,    // [500][512]
    const float* __restrict__ dec_b,    // [500]
    const int* __restrict__ tgt,        // [256]
    float* __restrict__ out)            // [256]
{
  const int w = threadIdx.x >> 6, l = threadIdx.x & 63;
  const int b = blockIdx.x * 4 + w;
  const int t = tgt[b];
  float s = 0.f;
#pragma unroll
  for (int i = 0; i < 8; ++i) {
    const int k = l + i * 64;
    s += hfinal[(size_t)b * 512 + k] * dec_W[(size_t)t * 512 + k];
  }
#pragma unroll
  for (int m = 32; m; m >>= 1) s += __shfl_xor(s, m, 64);
  if (l == 0) out[b] = sigf(s + dec_b[t]);
}

// ---------------------------------------------------------------------------
extern "C" void kernel_launch(void* const* d_in, const int* in_sizes, int n_in,
                              void* d_out, int out_size, void* d_ws, size_t ws_size,
                              hipStream_t stream) {
  (void)in_sizes; (void)n_in; (void)out_size; (void)ws_size;
  const int*   inp       = (const int*)d_in[0];
  const int*   target_id = (const int*)d_in[1];
  const int*   uid       = (const int*)d_in[2];
  const int*   sid       = (const int*)d_in[3];
  // d_in[4] attempt_sequence: unused by reference
  const float* enc_emb   = (const float*)d_in[5];
  const float* user_emb  = (const float*)d_in[6];
  const float* skill_emb = (const float*)d_in[7];
  const float* mf_W      = (const float*)d_in[8];
  const float* mf_b      = (const float*)d_in[9];
  const float* W_ih      = (const float*)d_in[10];
  const float* W_hh      = (const float*)d_in[11];
  const float* b_ih      = (const float*)d_in[12];
  const float* b_hh      = (const float*)d_in[13];
  const float* dec_W     = (const float*)d_in[14];
  const float* dec_b     = (const float*)d_in[15];

  char* ws = (char*)d_ws;
  uint32_t* extCnt = (uint32_t*)(ws);                  //    12,800 B (padded s-counters)
  uint16_t* hbuf   = (uint16_t*)(ws + 16384);          //   524,288 B (bf16 tagged x2 buf)
  float*    hfinal = (float*)   (ws + 540672);         //   524,288 B
  uint16_t* encWb  = (uint16_t*)(ws + 1064960);        // 4,104,192 B (bf16)
  uint16_t* mfWb   = (uint16_t*)(ws + 5169152);        // 1,048,576 B
  uint16_t* ext    = (uint16_t*)(ws + 6217728);        // 52,428,800 B (total ~58.6 MB)

  // every call (in-graph => every replay): extCnt := 0; hbuf := 0xFF (tag=3,
  // never matches the first wanted tag 0 -> poison/replay-safe).
  hipMemsetAsync(extCnt, 0, 12800, stream);
  hipMemsetAsync(hbuf, 0xFF, 524288, stream);

  k_prep<<<2048, 256, 0, stream>>>(mf_W, mfWb);
  k_encW<<<512,  256, 0, stream>>>(enc_emb, W_ih, b_ih, b_hh, encWb);
  k_fused<<<1056, 256, 0, stream>>>(inp, W_hh, encWb, uid, sid, user_emb, skill_emb,
                                    mfWb, mf_b, ext, hbuf, hfinal, extCnt);
  k_dec<<<64, 256, 0, stream>>>(hfinal, dec_W, dec_b, target_id, (float*)d_out);
}

// Round 14
// 684.686 us; speedup vs baseline: 1.3934x; 1.0825x over previous
//
#include <hip/hip_runtime.h>
#include <stdint.h>

typedef __bf16 bf16x8 __attribute__((ext_vector_type(8)));
typedef float f32x4 __attribute__((ext_vector_type(4)));

#define MFMA16(a, b, c) __builtin_amdgcn_mfma_f32_16x16x32_bf16((a), (b), (c), 0, 0, 0)

__device__ __forceinline__ float sigf(float x) { return 1.f / (1.f + __expf(-x)); }
__device__ __forceinline__ float tanhfast(float x) { return 1.f - 2.f / (__expf(2.f * x) + 1.f); }
__device__ __forceinline__ float bf2f(uint16_t u) {
  union { float f; uint32_t i; } v; v.i = ((uint32_t)u) << 16; return v.f;
}
__device__ __forceinline__ uint16_t f2bf(float f) {
  union { float f; uint32_t i; } v; v.f = f;
  return (uint16_t)((v.i + 0x7FFFu + ((v.i >> 16) & 1u)) >> 16);
}
// 8 consecutive f32 -> bf16x8 (RNE); p must be 16B-aligned
__device__ __forceinline__ bf16x8 cvt8(const float* __restrict__ p) {
  f32x4 a = *(const f32x4*)p;
  f32x4 b = *(const f32x4*)(p + 4);
  bf16x8 r;
  r[0] = (__bf16)a[0]; r[1] = (__bf16)a[1]; r[2] = (__bf16)a[2]; r[3] = (__bf16)a[3];
  r[4] = (__bf16)b[0]; r[5] = (__bf16)b[1]; r[6] = (__bf16)b[2]; r[7] = (__bf16)b[3];
  return r;
}

// ---------------------------------------------------------------------------
// K0: mf_W f32 [512][1000] -> bf16 padded [512][1024]
// ---------------------------------------------------------------------------
__global__ __launch_bounds__(256) void k_prep(
    const float* __restrict__ mf_W, uint16_t* __restrict__ mfWb) {
  const int idx = blockIdx.x * 256 + threadIdx.x;   // 524288 total
  const int h = idx >> 10, k = idx & 1023;
  const float v = (k < 1000) ? mf_W[(size_t)h * 1000 + k] : 0.f;
  mfWb[idx] = f2bf(v);
}

// ---------------------------------------------------------------------------
// K1: encWb[v][col] = bf16( sum_k enc_emb[v][k]*W_ih[col][k] + b_ih + b_hh )
// ---------------------------------------------------------------------------
__global__ __launch_bounds__(256) void k_encW(
    const float* __restrict__ enc_emb,   // [1002][512]
    const float* __restrict__ W_ih,      // [2048][512]
    const float* __restrict__ b_ih,
    const float* __restrict__ b_hh,
    uint16_t* __restrict__ encWb)        // [1002][2048] bf16
{
  const int w = threadIdx.x >> 6, l = threadIdx.x & 63;
  const int mblk = blockIdx.x & 15;
  const int nblk = blockIdx.x >> 4;
  const int kg = l >> 4;
  const int arow = mblk * 64 + w * 16 + (l & 15);
  const bool rowok = arow < 1002;

  f32x4 acc[4] = {};
  for (int kk = 0; kk < 16; ++kk) {
    const int kc = kk * 32 + kg * 8;
    bf16x8 a = {};
    if (rowok) a = cvt8(enc_emb + (size_t)arow * 512 + kc);
#pragma unroll
    for (int n = 0; n < 4; ++n) {
      const int wrow = nblk * 64 + n * 16 + (l & 15);
      bf16x8 b = cvt8(W_ih + (size_t)wrow * 512 + kc);
      acc[n] = MFMA16(a, b, acc[n]);
    }
  }
  const int orow = mblk * 64 + w * 16 + kg * 4;
#pragma unroll
  for (int n = 0; n < 4; ++n) {
    const int col = nblk * 64 + n * 16 + (l & 15);
    const float bias = b_ih[col] + b_hh[col];
#pragma unroll
    for (int j = 0; j < 4; ++j) {
      const int rrow = orow + j;
      if (rrow < 1002) encWb[(size_t)rrow * 2048 + col] = f2bf(acc[n][j] + bias);
    }
  }
}

// ---------------------------------------------------------------------------
// K2-FUSED: blocks 0..255 = scan (round-13 tagged-data protocol); blocks
//     256..1055 = s-major ext GEMM (round-11, unchanged).
//     ROUND-14 CHANGE (scan gather only): PARALLEL-ISSUE tag-polls. Round-13
//     polled its 4 producers in sequential while-loops — after the last
//     producer lands at time T, the walk p1->p2->p3 still paid ~3 extra
//     LLC RTTs. Now all 8 loads are issued before any tag check (one
//     pipelined vmcnt window ~= 1 RTT); retries reload only stale producers.
//     Detect cost: T + 4xRTT  ->  T + ~1xRTT.
//     Tag protocol safety unchanged (see round-13 header proof).
// ---------------------------------------------------------------------------
__global__ __launch_bounds__(256, 2) void k_fused(
    const int* __restrict__ inp,        // [256][200]
    const float* __restrict__ W_hh,     // [2048][512] f32
    const uint16_t* __restrict__ encWb, // [1002][2048] bf16
    const int* __restrict__ uid, const int* __restrict__ sid,   // [51200]
    const float* __restrict__ user_emb,    // [50000][500]
    const float* __restrict__ skill_emb,   // [500][500]
    const uint16_t* __restrict__ mfWb,     // [512][1024] bf16
    const float* __restrict__ mf_b,        // [512]
    uint16_t* __restrict__ ext,         // [256*200][512] bf16
    uint16_t* __restrict__ hbuf,        // [2][256][512] bf16 tagged
    float* __restrict__ hfinal,         // [256][512] f32
    uint32_t* __restrict__ extCnt)      // [200] x 16-u32 stride (64B lines)
{
  __shared__ __align__(1024) char ldsbuf[65536];

  const int tid = threadIdx.x;
  const int w = tid >> 6, l = tid & 63, kg = l >> 4;

  if (blockIdx.x >= 256) {
    // ================= EXT role (s-major, round-11 verified) =================
    char* As = ldsbuf;   // [64 rows][1024B], XOR-swizzled
    const int bx = blockIdx.x - 256;
    const int s  = bx >> 2;      // timestep 0..199
    const int bq = bx & 3;       // batch quarter

    const int srow = tid >> 2;
    const int q = tid & 3;
    const int m = (bq * 64 + srow) * 200 + s;
    const float* up = user_emb + (size_t)uid[m] * 500;
    const float* sp = skill_emb + (size_t)sid[m] * 500;

    f32x4 acc[4][8] = {};

#pragma unroll
    for (int ks = 0; ks < 2; ++ks) {
      if (ks) __syncthreads();
#pragma unroll
      for (int j = 0; j < 16; ++j) {
        const int e0 = ks * 512 + q * 128 + j * 8;
        bf16x8 av = {};
        if (e0 + 8 <= 500) {
          av = cvt8(up + e0);
        } else if (e0 == 496) {
          f32x4 a4 = *(const f32x4*)(up + 496);
          f32x4 b4 = *(const f32x4*)sp;
          av[0] = (__bf16)a4[0]; av[1] = (__bf16)a4[1]; av[2] = (__bf16)a4[2]; av[3] = (__bf16)a4[3];
          av[4] = (__bf16)b4[0]; av[5] = (__bf16)b4[1]; av[6] = (__bf16)b4[2]; av[7] = (__bf16)b4[3];
        } else if (e0 + 8 <= 1000) {
          av = cvt8(sp + (e0 - 500));
        }
        const int kb = (q * 128 + j * 8) * 2;
        *(bf16x8*)(As + srow * 1024 + (kb ^ ((srow & 7) << 4))) = av;
      }
      __syncthreads();

      for (int kk = 0; kk < 16; ++kk) {
        bf16x8 a[4];
#pragma unroll
        for (int rf = 0; rf < 4; ++rf) {
          const int row = rf * 16 + (l & 15);
          a[rf] = *(const bf16x8*)(As + row * 1024 +
                                   ((kk * 64 + kg * 16) ^ ((row & 7) << 4)));
        }
#pragma unroll
        for (int n = 0; n < 8; ++n) {
          const int col = w * 128 + n * 16 + (l & 15);
          bf16x8 b = *(const bf16x8*)(mfWb + (size_t)col * 1024 + ks * 512 + kk * 32 + kg * 8);
#pragma unroll
          for (int rf = 0; rf < 4; ++rf)
            acc[rf][n] = MFMA16(a[rf], b, acc[rf][n]);
        }
      }
    }

#pragma unroll
    for (int rf = 0; rf < 4; ++rf)
#pragma unroll
      for (int n = 0; n < 8; ++n) {
        const int col = w * 128 + n * 16 + (l & 15);
        const float bias = mf_b[col];
#pragma unroll
        for (int j = 0; j < 4; ++j) {
          const int bl = rf * 16 + kg * 4 + j;
          const size_t grow = (size_t)(bq * 64 + bl) * 200 + s;
          ext[grow * 512 + col] = f2bf(acc[rf][n][j] + bias);
        }
      }
    asm volatile("s_waitcnt vmcnt(0)" ::: "memory");
    __syncthreads();
    if (tid == 0) {
      asm volatile("buffer_wbl2 sc1\n\ts_waitcnt vmcnt(0)" ::: "memory");
      __hip_atomic_fetch_add(extCnt + s * 16, 1u, __ATOMIC_RELAXED, __HIP_MEMORY_SCOPE_AGENT);
    }
    return;
  }

  // ================= SCAN role (tagged exchange, parallel polls) =============
  uint16_t* htgS        = (uint16_t*)ldsbuf;                   // 16,384 B swizzled
  float (*gbuf)[16][32] = (float(*)[16][32])(ldsbuf + 16384);  //  8,192 B
  float (*ctS)[32]      = (float(*)[32])(ldsbuf + 24576);      //  2,048 B
  int (*inpS)[200]      = (int(*)[200])(ldsbuf + 26624);       // 12,800 B

  const int c = blockIdx.x & 15;          // h-slice (32 h)
  const int r = blockIdx.x >> 4;          // rowgroup (16 batch rows)
  const int row0 = r * 16;

  // W_hh slice -> bf16 register fragments (persistent, 128 VGPRs)
  bf16x8 wfrag[16][2];
#pragma unroll
  for (int kk = 0; kk < 16; ++kk) {
#pragma unroll
    for (int n = 0; n < 2; ++n) {
      const int wrow = w * 512 + c * 32 + n * 16 + (l & 15);
      wfrag[kk][n] = cvt8(W_hh + (size_t)wrow * 512 + kk * 32 + kg * 8);
    }
  }
  for (int e = tid; e < 512; e += 256) ctS[e >> 5][e & 31] = 0.f;
  for (int e = tid; e < 2048; e += 256) ((uint64_t*)htgS)[e] = 0ull;   // htg(0)=0
  for (int e = tid; e < 16 * 200; e += 256)
    inpS[e / 200][e % 200] = inp[(row0 + e / 200) * 200 + (e % 200)];

  const int grow_ = l >> 2;             // gather: row, 16B chunk
  const int gch = l & 3;
  const int urr = tid >> 4;             // cell: row, 2 consecutive h
  const int uh2 = (tid & 15) << 1;
  const int ub = row0 + urr;

  __syncthreads();

  // ---- prologue: acc(t=0) from encWb; gated ep (ext[:,1]) via agent load
  f32x4 acc[2];
#pragma unroll
  for (int n = 0; n < 2; ++n)
#pragma unroll
    for (int j = 0; j < 4; ++j) {
      const int col = w * 512 + c * 32 + n * 16 + (l & 15);
      acc[n][j] = bf2f(encWb[(size_t)inpS[kg * 4 + j][0] * 2048 + col]);
    }
  while (__hip_atomic_load(extCnt + 16, __ATOMIC_RELAXED, __HIP_MEMORY_SCOPE_AGENT) < 4u)
    __builtin_amdgcn_s_sleep(1);
  uint32_t ep = __hip_atomic_load(
      (const uint32_t*)(ext + (size_t)ub * 200 * 512 + 512 + c * 32 + uh2),
      __ATOMIC_RELAXED, __HIP_MEMORY_SCOPE_AGENT);

  for (int t = 0; t < 200; ++t) {
    // ---- gather h(t): PARALLEL-ISSUE tag-polls (all 8 loads before checks)
    if (t > 0) {
      const uint32_t tag = (uint32_t)((t >> 1) & 3);
      const uint64_t pat64 = ((uint64_t)((tag & 1u) | ((tag >> 1) << 16))) * 0x0000000100000001ull;
      const uint16_t* hb = hbuf + (size_t)(t & 1) * (256 * 512);
      const uint64_t* sp[4];
      uint64_t v[4][2];
#pragma unroll
      for (int p = 0; p < 4; ++p) {
        sp[p] = (const uint64_t*)(hb + (size_t)(row0 + grow_) * 512 + (w * 4 + p) * 32 + gch * 8);
        v[p][0] = __hip_atomic_load(sp[p],     __ATOMIC_RELAXED, __HIP_MEMORY_SCOPE_AGENT);
        v[p][1] = __hip_atomic_load(sp[p] + 1, __ATOMIC_RELAXED, __HIP_MEMORY_SCOPE_AGENT);
      }
#pragma unroll
      for (int p = 0; p < 4; ++p) {
        while ((v[p][0] & 0x0001000100010001ull) != pat64 ||
               (v[p][1] & 0x0001000100010001ull) != pat64) {
          __builtin_amdgcn_s_sleep(1);
          v[p][0] = __hip_atomic_load(sp[p],     __ATOMIC_RELAXED, __HIP_MEMORY_SCOPE_AGENT);
          v[p][1] = __hip_atomic_load(sp[p] + 1, __ATOMIC_RELAXED, __HIP_MEMORY_SCOPE_AGENT);
        }
      }
      // swizzled LDS writes (bank pattern: 2-way max = free)
#pragma unroll
      for (int p = 0; p < 4; ++p) {
        const int prod = w * 4 + p;
        const int baddr = grow_ * 1024 + (((prod * 64) + gch * 16) ^ ((grow_ & 7) << 4));
        *(uint64_t*)((char*)htgS + baddr)     = v[p][0];
        *(uint64_t*)((char*)htgS + baddr + 8) = v[p][1];
      }
    }
    __syncthreads();

    // ---- gates = acc(prefetched encW) + htg @ W_hh_slice^T
    const int ar = l & 15;
#pragma unroll
    for (int kk = 0; kk < 16; ++kk) {
      bf16x8 a = *(const bf16x8*)((char*)htgS + ar * 1024 +
                                  ((kk * 64 + kg * 16) ^ ((ar & 7) << 4)));
      acc[0] = MFMA16(a, wfrag[kk][0], acc[0]);
      acc[1] = MFMA16(a, wfrag[kk][1], acc[1]);
    }
#pragma unroll
    for (int n = 0; n < 2; ++n)
#pragma unroll
      for (int j = 0; j < 4; ++j)
        gbuf[w][kg * 4 + j][n * 16 + (l & 15)] = acc[n][j];
    __syncthreads();

    // ---- cell update: thread -> (row urr, 2 consecutive h); TAGGED store
    {
      float hv[2];
#pragma unroll
      for (int p = 0; p < 2; ++p) {
        const int h = uh2 + p;
        const float ig = sigf(gbuf[0][urr][h]);
        const float fg = sigf(gbuf[1][urr][h]);
        const float gg = tanhfast(gbuf[2][urr][h]);
        const float og = sigf(gbuf[3][urr][h]);
        const float cv = fg * ctS[urr][h] + ig * gg;
        ctS[urr][h] = cv;
        hv[p] = og * tanhfast(cv);
      }
      if (t < 199) {
        // pre-gate for step t+1: htg = ht * sigmoid(ext[:, t+1, :]);
        // embed gen tag ((t+1)>>1)&3 in the two bf16 LSBs (<=1 ulp each)
        const float g0 = sigf(bf2f((uint16_t)(ep & 0xFFFFu)));
        const float g1 = sigf(bf2f((uint16_t)(ep >> 16)));
        const uint32_t tagn = (uint32_t)(((t + 1) >> 1) & 3);
        const uint32_t tpat = (tagn & 1u) | ((tagn >> 1) << 16);
        uint32_t pk = (uint32_t)f2bf(hv[0] * g0) | ((uint32_t)f2bf(hv[1] * g1) << 16);
        pk = (pk & ~0x00010001u) | tpat;
        uint32_t* hw = (uint32_t*)(hbuf + (size_t)((t + 1) & 1) * (256 * 512) +
                                   (size_t)ub * 512 + c * 32 + uh2);
        __hip_atomic_store(hw, pk, __ATOMIC_RELAXED, __HIP_MEMORY_SCOPE_AGENT);
      } else {
        hfinal[(size_t)ub * 512 + c * 32 + uh2]     = hv[0];
        hfinal[(size_t)ub * 512 + c * 32 + uh2 + 1] = hv[1];
      }
    }
    // NO drain, NO barrier, NO flag — tags carry the ordering.

    // ---- prefetch for step t+1 (hides under next step's tag-poll)
    if (t < 199) {
      const int tn = t + 1;
#pragma unroll
      for (int n = 0; n < 2; ++n)
#pragma unroll
        for (int j = 0; j < 4; ++j) {
          const int col = w * 512 + c * 32 + n * 16 + (l & 15);
          acc[n][j] = bf2f(encWb[(size_t)inpS[kg * 4 + j][tn] * 2048 + col]);
        }
      const int te = (t + 2 < 200) ? t + 2 : 199;
      while (__hip_atomic_load(extCnt + te * 16, __ATOMIC_RELAXED, __HIP_MEMORY_SCOPE_AGENT) < 4u)
        __builtin_amdgcn_s_sleep(1);
      ep = __hip_atomic_load(
          (const uint32_t*)(ext + (size_t)ub * 200 * 512 + (size_t)te * 512 + c * 32 + uh2),
          __ATOMIC_RELAXED, __HIP_MEMORY_SCOPE_AGENT);
    }
  }
}

// ---------------------------------------------------------------------------
// K4: out[b] = sigmoid( dot(hfinal[b], dec_W[tgt[b]]) + dec_b[tgt[b]] )
// ---------------------------------------------------------------------------
__global__ __launch_bounds__(256) void k_dec(
    const float* __restrict__ hfinal,   // [256][512]
    const float* __restrict__ dec_W,    // [500][512]
    const float* __restrict__ dec_b,    // [500]
    const int* __restrict__ tgt,        // [256]
    float* __restrict__ out)            // [256]
{
  const int w = threadIdx.x >> 6, l = threadIdx.x & 63;
  const int b = blockIdx.x * 4 + w;
  const int t = tgt[b];
  float s = 0.f;
#pragma unroll
  for (int i = 0; i < 8; ++i) {
    const int k = l + i * 64;
    s += hfinal[(size_t)b * 512 + k] * dec_W[(size_t)t * 512 + k];
  }
#pragma unroll
  for (int m = 32; m; m >>= 1) s += __shfl_xor(s, m, 64);
  if (l == 0) out[b] = sigf(s + dec_b[t]);
}

// ---------------------------------------------------------------------------
extern "C" void kernel_launch(void* const* d_in, const int* in_sizes, int n_in,
                              void* d_out, int out_size, void* d_ws, size_t ws_size,
                              hipStream_t stream) {
  (void)in_sizes; (void)n_in; (void)out_size; (void)ws_size;
  const int*   inp       = (const int*)d_in[0];
  const int*   target_id = (const int*)d_in[1];
  const int*   uid       = (const int*)d_in[2];
  const int*   sid       = (const int*)d_in[3];
  // d_in[4] attempt_sequence: unused by reference
  const float* enc_emb   = (const float*)d_in[5];
  const float* user_emb  = (const float*)d_in[6];
  const float* skill_emb = (const float*)d_in[7];
  const float* mf_W      = (const float*)d_in[8];
  const float* mf_b      = (const float*)d_in[9];
  const float* W_ih      = (const float*)d_in[10];
  const float* W_hh      = (const float*)d_in[11];
  const float* b_ih      = (const float*)d_in[12];
  const float* b_hh      = (const float*)d_in[13];
  const float* dec_W     = (const float*)d_in[14];
  const float* dec_b     = (const float*)d_in[15];

  char* ws = (char*)d_ws;
  uint32_t* extCnt = (uint32_t*)(ws);                  //    12,800 B (padded s-counters)
  uint16_t* hbuf   = (uint16_t*)(ws + 16384);          //   524,288 B (bf16 tagged x2 buf)
  float*    hfinal = (float*)   (ws + 540672);         //   524,288 B
  uint16_t* encWb  = (uint16_t*)(ws + 1064960);        // 4,104,192 B (bf16)
  uint16_t* mfWb   = (uint16_t*)(ws + 5169152);        // 1,048,576 B
  uint16_t* ext    = (uint16_t*)(ws + 6217728);        // 52,428,800 B (total ~58.6 MB)

  // every call (in-graph => every replay): extCnt := 0; hbuf := 0xFF (tag=3,
  // never matches the first wanted tag 0 -> poison/replay-safe).
  hipMemsetAsync(extCnt, 0, 12800, stream);
  hipMemsetAsync(hbuf, 0xFF, 524288, stream);

  k_prep<<<2048, 256, 0, stream>>>(mf_W, mfWb);
  k_encW<<<512,  256, 0, stream>>>(enc_emb, W_ih, b_ih, b_hh, encWb);
  k_fused<<<1056, 256, 0, stream>>>(inp, W_hh, encWb, uid, sid, user_emb, skill_emb,
                                    mfWb, mf_b, ext, hbuf, hfinal, extCnt);
  k_dec<<<64, 256, 0, stream>>>(hfinal, dec_W, dec_b, target_id, (float*)d_out);
}